// Round 8
// baseline (285.383 us; speedup 1.0000x reference)
//
#include <hip/hip_runtime.h>
#include <hip/hip_bf16.h>

#define B 4
#define T 4096
#define D 512
#define KKEEP 1024
#define RSQRT_D 0.044194173824159216f  // 1/sqrt(512)

// Monotone float->uint map: preserves total order.
__device__ __forceinline__ unsigned f2ord(float f) {
    unsigned u = __float_as_uint(f);
    return (u & 0x80000000u) ? ~u : (u | 0x80000000u);
}
__device__ __forceinline__ float ord2f(unsigned o) {
    return __uint_as_float((o & 0x80000000u) ? (o ^ 0x80000000u) : ~o);
}

// ---------------------------------------------------------------------------
// K1: qpart[b][z][j] = sum_{d in 64-chunk z} h[b,T-1,d] * Wq[d,j]
// 32 blocks x 512 thr; Wq read spread wide, column-coalesced.
__global__ __launch_bounds__(512) void k_qpart(const float* __restrict__ h,
                                               const float* __restrict__ Wq,
                                               float* __restrict__ qpart) {
    int blk = blockIdx.x, tid = threadIdx.x;
    int b = blk >> 3, z = blk & 7, d0 = z * 64;
    __shared__ float hs[64];
    if (tid < 64) hs[tid] = h[((size_t)b * T + (T - 1)) * D + d0 + tid];
    __syncthreads();
    float acc = 0.f;
#pragma unroll 8
    for (int d = 0; d < 64; ++d) acc += hs[d] * Wq[(size_t)(d0 + d) * D + tid];
    qpart[(b * 8 + z) * D + tid] = acc;
}

// ---------------------------------------------------------------------------
// K2: q = sum_z qpart + bq;  wvec[b][d] = rsqrtD*(Wk[d,:].q) for d in z-chunk;
// cvec[b] = rsqrtD*(bk.q).  32 blocks x 512 thr (8 waves x 8 rows each).
__global__ __launch_bounds__(512) void k_wk(const float* __restrict__ Wk,
                                            const float* __restrict__ bk,
                                            const float* __restrict__ bq,
                                            const float* __restrict__ qpart,
                                            float* __restrict__ wvec,
                                            float* __restrict__ cvec) {
    int blk = blockIdx.x, tid = threadIdx.x;
    int b = blk >> 3, z = blk & 7;
    int lane = tid & 63, wave = tid >> 6;
    __shared__ float qs[D];
    float s = 0.f;
#pragma unroll 8
    for (int z2 = 0; z2 < 8; ++z2) s += qpart[(b * 8 + z2) * D + tid];
    qs[tid] = s + bq[tid];
    __syncthreads();
    const float4* q4 = (const float4*)qs;
    for (int r = 0; r < 8; ++r) {
        int d = z * 64 + wave * 8 + r;
        const float4* w4 = (const float4*)(Wk + (size_t)d * D);
        float4 a = w4[lane], qa = q4[lane];
        float4 b4 = w4[lane + 64], qb = q4[lane + 64];
        float acc = a.x*qa.x + a.y*qa.y + a.z*qa.z + a.w*qa.w
                  + b4.x*qb.x + b4.y*qb.y + b4.z*qb.z + b4.w*qb.w;
        for (int off = 32; off; off >>= 1) acc += __shfl_down(acc, off);
        if (lane == 0) wvec[b * D + d] = acc * RSQRT_D;
    }
    if (z == 0 && wave == 0) {
        float a = 0.f;
        for (int k = lane; k < D; k += 64) a += bk[k] * qs[k];
        for (int off = 32; off; off >>= 1) a += __shfl_down(a, off);
        if (lane == 0) cvec[b] = a * RSQRT_D;
    }
}

// ---------------------------------------------------------------------------
// K3: sc[b,s] = h[b,s,:] . wvec[b] + cvec[b].  grid (B,128) x 256 thr,
// 4 waves x 8 rows = 32 rows/block; float4 lane loads + shfl reduce.
__global__ __launch_bounds__(256) void k_scores(const float* __restrict__ h,
                                                const float* __restrict__ wvec,
                                                const float* __restrict__ cvec,
                                                float* __restrict__ sc) {
    int b = blockIdx.x, s0 = blockIdx.y * 32, tid = threadIdx.x;
    int lane = tid & 63, wave = tid >> 6;
    __shared__ float wsv[D];
    wsv[tid] = wvec[b * D + tid];
    wsv[tid + 256] = wvec[b * D + tid + 256];
    __syncthreads();
    const float4* w4 = (const float4*)wsv;
    float cv = cvec[b];
    for (int r = 0; r < 8; ++r) {
        int s = s0 + wave * 8 + r;
        const float4* h4 = (const float4*)(h + ((size_t)b * T + s) * D);
        float4 a = h4[lane], wa = w4[lane];
        float4 b4 = h4[lane + 64], wb = w4[lane + 64];
        float acc = a.x*wa.x + a.y*wa.y + a.z*wa.z + a.w*wa.w
                  + b4.x*wb.x + b4.y*wb.y + b4.z*wb.z + b4.w*wb.w;
        for (int off = 32; off; off >>= 1) acc += __shfl_down(acc, off);
        if (lane == 0) sc[b * T + s] = acc + cv;
    }
}

// ---------------------------------------------------------------------------
// K4: per batch — exact top-1024 radix select (proven), then FUSED weighted
// gather from the LDS sel-list: wsum[b,:] = (1/denom) * sum_t w_t * h[b,idx_t,:].
// 4 blocks x 1024 thr.
__global__ __launch_bounds__(1024) void k_selgather(const float* __restrict__ h,
                                                    const float* __restrict__ sc,
                                                    float* __restrict__ wsum) {
    int b = blockIdx.x, tid = threadIdx.x;
    int lane = tid & 63, wave = tid >> 6;
    __shared__ unsigned ordk[T];      // 16KB
    __shared__ unsigned tieI[T];      // 16KB (redf aliases first 4KB later)
    __shared__ unsigned sI[KKEEP];    // 4KB
    __shared__ float sW[KKEEP];       // 4KB
    __shared__ int hist[256];         // 1KB
    __shared__ float red[16];
    __shared__ unsigned sh_pv;
    __shared__ int sh_r, sh_cnt, sh_tiecnt;
    __shared__ float sh_max, sh_inv;

    float sv[4];
    float lmax = -INFINITY;
#pragma unroll
    for (int k = 0; k < 4; ++k) {
        int i = tid + k * 1024;
        float v = sc[b * T + i];
        sv[k] = v;
        ordk[i] = f2ord(v);
        lmax = fmaxf(lmax, v);
    }
    for (int off = 32; off; off >>= 1) lmax = fmaxf(lmax, __shfl_down(lmax, off));
    if (lane == 0) red[wave] = lmax;
    __syncthreads();
    if (tid == 0) {
        float m = red[0];
        for (int w = 1; w < 16; ++w) m = fmaxf(m, red[w]);
        sh_max = m; sh_pv = 0; sh_r = KKEEP; sh_cnt = 0; sh_tiecnt = 0;
    }
    __syncthreads();

    for (int p = 24; p >= 0; p -= 8) {
        if (tid < 256) hist[tid] = 0;
        __syncthreads();
        unsigned pv = sh_pv;
#pragma unroll
        for (int k = 0; k < 4; ++k) {
            unsigned key = ordk[tid + k * 1024];
            bool act = (p == 24) || ((key >> (p + 8)) == pv);
            if (act) atomicAdd(&hist[(key >> p) & 255], 1);
        }
        __syncthreads();
        if (tid < 64) {  // wave 0: suffix-scan 256 bins, locate rank r
            int r = sh_r;
            int c0 = hist[tid*4], c1 = hist[tid*4+1], c2 = hist[tid*4+2], c3 = hist[tid*4+3];
            int ssum = c0 + c1 + c2 + c3;
            int cum = ssum;
            for (int off = 1; off < 64; off <<= 1) {
                int v = __shfl_down(cum, off);
                if (tid + off < 64) cum += v;
            }
            int base = cum - ssum;
            if (base < r && r <= cum) {  // exactly one lane
                int d, sg;
                if (r <= base + c3)                { d = 3; sg = base; }
                else if (r <= base + c3 + c2)      { d = 2; sg = base + c3; }
                else if (r <= base + c3 + c2 + c1) { d = 1; sg = base + c3 + c2; }
                else                               { d = 0; sg = base + c3 + c2 + c1; }
                sh_pv = (pv << 8) | (unsigned)(tid * 4 + d);
                sh_r = r - sg;
            }
        }
        __syncthreads();
    }

    unsigned vstar = sh_pv;
    int rtie = sh_r;
    float gmax = sh_max;

#pragma unroll
    for (int k = 0; k < 4; ++k) {
        int i = tid + k * 1024;
        unsigned key = ordk[i];
        if (key > vstar) {
            int pos = atomicAdd(&sh_cnt, 1);
            sI[pos] = (unsigned)i;
            sW[pos] = __expf(sv[k] - gmax);
        } else if (key == vstar) {
            int pos = atomicAdd(&sh_tiecnt, 1);
            tieI[pos] = (unsigned)i;
        }
    }
    __syncthreads();

    int tcnt = sh_tiecnt;
    float tw = __expf(ord2f(vstar) - gmax);
    for (int t = tid; t < tcnt; t += 1024) {
        unsigned my = tieI[t];
        int rank = 0;
        for (int o = 0; o < tcnt; ++o) rank += (tieI[o] < my);
        if (rank < rtie) {  // rtie smallest-index ties included
            int pos = atomicAdd(&sh_cnt, 1);
            sI[pos] = my;
            sW[pos] = tw;
        }
    }
    __syncthreads();

    // Softmax denominator over the 1024 selected (weights stay unnormalized).
    float lsum = sW[tid];
    for (int off = 32; off; off >>= 1) lsum += __shfl_down(lsum, off);
    if (lane == 0) red[wave] = lsum;
    __syncthreads();
    if (tid == 0) {
        float ssum = 0.f;
        for (int w = 0; w < 16; ++w) ssum += red[w];
        sh_inv = 1.0f / ssum;
    }
    __syncthreads();

    // Fused gather: wsum[d] = sh_inv * sum_t sW[t] * h[b, sI[t], d].
    // d = tid&511 coalesced across lanes; sI/sW broadcast-read from LDS.
    float* redf = (float*)tieI;  // alias: tie phase complete
    int d = tid & 511, g = tid >> 9;
    float acc = 0.f;
    for (int t = g; t < KKEEP; t += 2)
        acc += sW[t] * h[((size_t)b * T + sI[t]) * D + d];
    redf[tid] = acc;
    __syncthreads();
    if (tid < D) wsum[b * D + tid] = (redf[tid] + redf[tid + D]) * sh_inv;
}

// ---------------------------------------------------------------------------
// K5: out[b,j] = wsum[b,:] . Wv[:,j] + bv[j].  grid (B,4) x 128 thr.
__global__ __launch_bounds__(128) void k_out(const float* __restrict__ wsum,
                                             const float* __restrict__ Wv,
                                             const float* __restrict__ bv,
                                             float* __restrict__ out) {
    int b = blockIdx.x, tid = threadIdx.x;
    int j = blockIdx.y * 128 + tid;
    __shared__ float wsv[D];
    for (int i = tid; i < D; i += 128) wsv[i] = wsum[b * D + i];
    __syncthreads();
    float acc = bv[j];
#pragma unroll 8
    for (int d = 0; d < D; ++d) acc += wsv[d] * Wv[(size_t)d * D + j];
    out[b * D + j] = acc;
}

// ---------------------------------------------------------------------------
extern "C" void kernel_launch(void* const* d_in, const int* in_sizes, int n_in,
                              void* d_out, int out_size, void* d_ws, size_t ws_size,
                              hipStream_t stream) {
    const float* h  = (const float*)d_in[0];
    const float* Wq = (const float*)d_in[1];
    const float* bq = (const float*)d_in[2];
    const float* Wk = (const float*)d_in[3];
    const float* bk = (const float*)d_in[4];
    const float* Wv = (const float*)d_in[5];
    const float* bv = (const float*)d_in[6];
    float* out = (float*)d_out;

    float* ws = (float*)d_ws;
    float* qpart = ws;           // B*8*D = 16384
    float* wvec  = ws + 16384;   // B*D   = 2048
    float* cvec  = ws + 18432;   // B (pad 64)
    float* sc    = ws + 18496;   // B*T   = 16384
    float* wsum  = ws + 34880;   // B*D   = 2048

    k_qpart<<<dim3(32), 512, 0, stream>>>(h, Wq, qpart);
    k_wk<<<dim3(32), 512, 0, stream>>>(Wk, bk, bq, qpart, wvec, cvec);
    k_scores<<<dim3(B, 128), 256, 0, stream>>>(h, wvec, cvec, sc);
    k_selgather<<<dim3(B), 1024, 0, stream>>>(h, sc, wsum);
    k_out<<<dim3(B, 4), 128, 0, stream>>>(wsum, Wv, bv, out);
}

// Round 9
// 147.879 us; speedup vs baseline: 1.9298x; 1.9298x over previous
//
#include <hip/hip_runtime.h>
#include <hip/hip_bf16.h>

#define B 4
#define T 4096
#define D 512
#define KKEEP 1024
#define RSQRT_D 0.044194173824159216f  // 1/sqrt(512)

// Monotone float->uint map: preserves total order.
__device__ __forceinline__ unsigned f2ord(float f) {
    unsigned u = __float_as_uint(f);
    return (u & 0x80000000u) ? ~u : (u | 0x80000000u);
}
__device__ __forceinline__ float ord2f(unsigned o) {
    return __uint_as_float((o & 0x80000000u) ? (o ^ 0x80000000u) : ~o);
}

// ---------------------------------------------------------------------------
// K1: qpart[b][z][j] = sum_{d in 64-chunk z} h[b,T-1,d] * Wq[d,j]
__global__ __launch_bounds__(512) void k_qpart(const float* __restrict__ h,
                                               const float* __restrict__ Wq,
                                               float* __restrict__ qpart) {
    int blk = blockIdx.x, tid = threadIdx.x;
    int b = blk >> 3, z = blk & 7, d0 = z * 64;
    __shared__ float hs[64];
    if (tid < 64) hs[tid] = h[((size_t)b * T + (T - 1)) * D + d0 + tid];
    __syncthreads();
    float acc = 0.f;
#pragma unroll 8
    for (int d = 0; d < 64; ++d) acc += hs[d] * Wq[(size_t)(d0 + d) * D + tid];
    qpart[(b * 8 + z) * D + tid] = acc;
}

// ---------------------------------------------------------------------------
// K2: q = sum_z qpart + bq;  wvec[b][d] = rsqrtD*(Wk[d,:].q);  cvec[b] = rsqrtD*(bk.q)
__global__ __launch_bounds__(512) void k_wk(const float* __restrict__ Wk,
                                            const float* __restrict__ bk,
                                            const float* __restrict__ bq,
                                            const float* __restrict__ qpart,
                                            float* __restrict__ wvec,
                                            float* __restrict__ cvec) {
    int blk = blockIdx.x, tid = threadIdx.x;
    int b = blk >> 3, z = blk & 7;
    int lane = tid & 63, wave = tid >> 6;
    __shared__ float qs[D];
    float s = 0.f;
#pragma unroll 8
    for (int z2 = 0; z2 < 8; ++z2) s += qpart[(b * 8 + z2) * D + tid];
    qs[tid] = s + bq[tid];
    __syncthreads();
    const float4* q4 = (const float4*)qs;
    for (int r = 0; r < 8; ++r) {
        int d = z * 64 + wave * 8 + r;
        const float4* w4 = (const float4*)(Wk + (size_t)d * D);
        float4 a = w4[lane], qa = q4[lane];
        float4 b4 = w4[lane + 64], qb = q4[lane + 64];
        float acc = a.x*qa.x + a.y*qa.y + a.z*qa.z + a.w*qa.w
                  + b4.x*qb.x + b4.y*qb.y + b4.z*qb.z + b4.w*qb.w;
        for (int off = 32; off; off >>= 1) acc += __shfl_down(acc, off);
        if (lane == 0) wvec[b * D + d] = acc * RSQRT_D;
    }
    if (z == 0 && wave == 0) {
        float a = 0.f;
        for (int k = lane; k < D; k += 64) a += bk[k] * qs[k];
        for (int off = 32; off; off >>= 1) a += __shfl_down(a, off);
        if (lane == 0) cvec[b] = a * RSQRT_D;
    }
}

// ---------------------------------------------------------------------------
// K3: sc[b,s] = h[b,s,:] . wvec[b] + cvec[b].  grid (B,128) x 256 thr.
__global__ __launch_bounds__(256) void k_scores(const float* __restrict__ h,
                                                const float* __restrict__ wvec,
                                                const float* __restrict__ cvec,
                                                float* __restrict__ sc) {
    int b = blockIdx.x, s0 = blockIdx.y * 32, tid = threadIdx.x;
    int lane = tid & 63, wave = tid >> 6;
    __shared__ float wsv[D];
    wsv[tid] = wvec[b * D + tid];
    wsv[tid + 256] = wvec[b * D + tid + 256];
    __syncthreads();
    const float4* w4 = (const float4*)wsv;
    float cv = cvec[b];
    for (int r = 0; r < 8; ++r) {
        int s = s0 + wave * 8 + r;
        const float4* h4 = (const float4*)(h + ((size_t)b * T + s) * D);
        float4 a = h4[lane], wa = w4[lane];
        float4 b4 = h4[lane + 64], wb = w4[lane + 64];
        float acc = a.x*wa.x + a.y*wa.y + a.z*wa.z + a.w*wa.w
                  + b4.x*wb.x + b4.y*wb.y + b4.z*wb.z + b4.w*wb.w;
        for (int off = 32; off; off >>= 1) acc += __shfl_down(acc, off);
        if (lane == 0) sc[b * T + s] = acc + cv;
    }
}

// ---------------------------------------------------------------------------
// K4: per batch — exact top-1024 radix select; write normalized (idx, weight).
__global__ __launch_bounds__(1024) void k_select(const float* __restrict__ sc,
                                                 unsigned* __restrict__ selI,
                                                 float* __restrict__ selW) {
    int b = blockIdx.x, tid = threadIdx.x;
    int lane = tid & 63, wave = tid >> 6;
    __shared__ unsigned ordk[T];      // 16KB
    __shared__ unsigned tieI[T];      // 16KB
    __shared__ unsigned sI[KKEEP];    // 4KB
    __shared__ float sW[KKEEP];       // 4KB
    __shared__ int hist[256];
    __shared__ float red[16];
    __shared__ unsigned sh_pv;
    __shared__ int sh_r, sh_cnt, sh_tiecnt;
    __shared__ float sh_max, sh_inv;

    float sv[4];
    float lmax = -INFINITY;
#pragma unroll
    for (int k = 0; k < 4; ++k) {
        int i = tid + k * 1024;
        float v = sc[b * T + i];
        sv[k] = v;
        ordk[i] = f2ord(v);
        lmax = fmaxf(lmax, v);
    }
    for (int off = 32; off; off >>= 1) lmax = fmaxf(lmax, __shfl_down(lmax, off));
    if (lane == 0) red[wave] = lmax;
    __syncthreads();
    if (tid == 0) {
        float m = red[0];
        for (int w = 1; w < 16; ++w) m = fmaxf(m, red[w]);
        sh_max = m; sh_pv = 0; sh_r = KKEEP; sh_cnt = 0; sh_tiecnt = 0;
    }
    __syncthreads();

    for (int p = 24; p >= 0; p -= 8) {
        if (tid < 256) hist[tid] = 0;
        __syncthreads();
        unsigned pv = sh_pv;
#pragma unroll
        for (int k = 0; k < 4; ++k) {
            unsigned key = ordk[tid + k * 1024];
            bool act = (p == 24) || ((key >> (p + 8)) == pv);
            if (act) atomicAdd(&hist[(key >> p) & 255], 1);
        }
        __syncthreads();
        if (tid < 64) {  // wave 0: suffix-scan 256 bins, locate rank r
            int r = sh_r;
            int c0 = hist[tid*4], c1 = hist[tid*4+1], c2 = hist[tid*4+2], c3 = hist[tid*4+3];
            int ssum = c0 + c1 + c2 + c3;
            int cum = ssum;
            for (int off = 1; off < 64; off <<= 1) {
                int v = __shfl_down(cum, off);
                if (tid + off < 64) cum += v;
            }
            int base = cum - ssum;
            if (base < r && r <= cum) {  // exactly one lane
                int d, sg;
                if (r <= base + c3)                { d = 3; sg = base; }
                else if (r <= base + c3 + c2)      { d = 2; sg = base + c3; }
                else if (r <= base + c3 + c2 + c1) { d = 1; sg = base + c3 + c2; }
                else                               { d = 0; sg = base + c3 + c2 + c1; }
                sh_pv = (pv << 8) | (unsigned)(tid * 4 + d);
                sh_r = r - sg;
            }
        }
        __syncthreads();
    }

    unsigned vstar = sh_pv;
    int rtie = sh_r;
    float gmax = sh_max;

#pragma unroll
    for (int k = 0; k < 4; ++k) {
        int i = tid + k * 1024;
        unsigned key = ordk[i];
        if (key > vstar) {
            int pos = atomicAdd(&sh_cnt, 1);
            sI[pos] = (unsigned)i;
            sW[pos] = __expf(sv[k] - gmax);
        } else if (key == vstar) {
            int pos = atomicAdd(&sh_tiecnt, 1);
            tieI[pos] = (unsigned)i;
        }
    }
    __syncthreads();

    int tcnt = sh_tiecnt;
    float tw = __expf(ord2f(vstar) - gmax);
    for (int t = tid; t < tcnt; t += 1024) {
        unsigned my = tieI[t];
        int rank = 0;
        for (int o = 0; o < tcnt; ++o) rank += (tieI[o] < my);
        if (rank < rtie) {  // rtie smallest-index ties included
            int pos = atomicAdd(&sh_cnt, 1);
            sI[pos] = my;
            sW[pos] = tw;
        }
    }
    __syncthreads();

    float lsum = sW[tid];
    for (int off = 32; off; off >>= 1) lsum += __shfl_down(lsum, off);
    if (lane == 0) red[wave] = lsum;
    __syncthreads();
    if (tid == 0) {
        float ssum = 0.f;
        for (int w = 0; w < 16; ++w) ssum += red[w];
        sh_inv = 1.0f / ssum;
    }
    __syncthreads();
    selI[b * KKEEP + tid] = sI[tid];
    selW[b * KKEEP + tid] = sW[tid] * sh_inv;
}

// ---------------------------------------------------------------------------
// K5: part[b][y][:] = sum over 32 selected rows of w * h[b,idx,:]
// grid (B,32) x 512 thr = 4 groups x 128 lanes; no atomics.
__global__ __launch_bounds__(512) void k_wsum(const float* __restrict__ h,
                                              const unsigned* __restrict__ selI,
                                              const float* __restrict__ selW,
                                              float* __restrict__ part) {
    int b = blockIdx.x, y = blockIdx.y, tid = threadIdx.x;
    int g = tid >> 7, l = tid & 127;
    int e0 = y * 32;
    __shared__ float4 red4[512];
    float4 acc = make_float4(0.f, 0.f, 0.f, 0.f);
    for (int e = g; e < 32; e += 4) {
        unsigned s = selI[b * KKEEP + e0 + e];
        float w = selW[b * KKEEP + e0 + e];
        float4 v = ((const float4*)(h + ((size_t)b * T + s) * D))[l];
        acc.x += w * v.x; acc.y += w * v.y; acc.z += w * v.z; acc.w += w * v.w;
    }
    red4[tid] = acc;
    __syncthreads();
    if (tid < 128) {
        float4 a = red4[tid], b4 = red4[tid + 128], c = red4[tid + 256], d4 = red4[tid + 384];
        float4 r = make_float4(a.x + b4.x + c.x + d4.x, a.y + b4.y + c.y + d4.y,
                               a.z + b4.z + c.z + d4.z, a.w + b4.w + c.w + d4.w);
        ((float4*)part)[(b * 32 + y) * 128 + tid] = r;
    }
}

// ---------------------------------------------------------------------------
// K6: reduce 32 partials in LDS, then out[b,j] = wsum . Wv[:,j] + bv[j]
__global__ __launch_bounds__(256) void k_out(const float* __restrict__ part,
                                             const float* __restrict__ Wv,
                                             const float* __restrict__ bv,
                                             float* __restrict__ out) {
    int b = blockIdx.x, tid = threadIdx.x;
    int j = blockIdx.y * 256 + tid;
    __shared__ float ws_[D];
    for (int d = tid; d < D; d += 256) {
        float s = 0.f;
#pragma unroll 8
        for (int p = 0; p < 32; ++p) s += part[(size_t)(b * 32 + p) * D + d];
        ws_[d] = s;
    }
    __syncthreads();
    float acc = bv[j];
#pragma unroll 4
    for (int d = 0; d < D; ++d) acc += ws_[d] * Wv[(size_t)d * D + j];
    out[b * D + j] = acc;
}

// ---------------------------------------------------------------------------
extern "C" void kernel_launch(void* const* d_in, const int* in_sizes, int n_in,
                              void* d_out, int out_size, void* d_ws, size_t ws_size,
                              hipStream_t stream) {
    const float* h  = (const float*)d_in[0];
    const float* Wq = (const float*)d_in[1];
    const float* bq = (const float*)d_in[2];
    const float* Wk = (const float*)d_in[3];
    const float* bk = (const float*)d_in[4];
    const float* Wv = (const float*)d_in[5];
    const float* bv = (const float*)d_in[6];
    float* out = (float*)d_out;

    float* ws = (float*)d_ws;
    float* qpart   = ws;                       // B*8*D = 16384
    float* wvec    = ws + 16384;               // B*D   = 2048
    float* cvec    = ws + 18432;               // B (pad 64)
    float* sc      = ws + 18496;               // B*T   = 16384
    unsigned* selI = (unsigned*)(ws + 34880);  // B*KKEEP = 4096
    float* selW    = ws + 38976;               // B*KKEEP = 4096
    float* part    = ws + 43072;               // B*32*D = 65536

    k_qpart<<<dim3(32), 512, 0, stream>>>(h, Wq, qpart);
    k_wk<<<dim3(32), 512, 0, stream>>>(Wk, bk, bq, qpart, wvec, cvec);
    k_scores<<<dim3(B, 128), 256, 0, stream>>>(h, wvec, cvec, sc);
    k_select<<<dim3(B), 1024, 0, stream>>>(sc, selI, selW);
    k_wsum<<<dim3(B, 32), 512, 0, stream>>>(h, selI, selW, part);
    k_out<<<dim3(B, 2), 256, 0, stream>>>(part, Wv, bv, out);
}

// Round 11
// 114.812 us; speedup vs baseline: 2.4857x; 1.2880x over previous
//
#include <hip/hip_runtime.h>
#include <hip/hip_bf16.h>

#define B 4
#define T 4096
#define D 512
#define KKEEP 1024
#define RSQRT_D 0.044194173824159216f  // 1/sqrt(512)

// Monotone float->uint map: preserves total order.
__device__ __forceinline__ unsigned f2ord(float f) {
    unsigned u = __float_as_uint(f);
    return (u & 0x80000000u) ? ~u : (u | 0x80000000u);
}
__device__ __forceinline__ float ord2f(unsigned o) {
    return __uint_as_float((o & 0x80000000u) ? (o ^ 0x80000000u) : ~o);
}

// ---------------------------------------------------------------------------
// K1: qpart[b][z][j] = sum_{d in 64-chunk z} h[b,T-1,d] * Wq[d,j]
__global__ __launch_bounds__(512) void k_qpart(const float* __restrict__ h,
                                               const float* __restrict__ Wq,
                                               float* __restrict__ qpart) {
    int blk = blockIdx.x, tid = threadIdx.x;
    int b = blk >> 3, z = blk & 7, d0 = z * 64;
    __shared__ float hs[64];
    if (tid < 64) hs[tid] = h[((size_t)b * T + (T - 1)) * D + d0 + tid];
    __syncthreads();
    float acc = 0.f;
#pragma unroll 8
    for (int d = 0; d < 64; ++d) acc += hs[d] * Wq[(size_t)(d0 + d) * D + tid];
    qpart[(b * 8 + z) * D + tid] = acc;
}

// ---------------------------------------------------------------------------
// K2: q = sum_z qpart + bq;  wvec[b][d] = rsqrtD*(Wk[d,:].q);  cvec[b] = rsqrtD*(bk.q)
__global__ __launch_bounds__(512) void k_wk(const float* __restrict__ Wk,
                                            const float* __restrict__ bk,
                                            const float* __restrict__ bq,
                                            const float* __restrict__ qpart,
                                            float* __restrict__ wvec,
                                            float* __restrict__ cvec) {
    int blk = blockIdx.x, tid = threadIdx.x;
    int b = blk >> 3, z = blk & 7;
    int lane = tid & 63, wave = tid >> 6;
    __shared__ float qs[D];
    float s = 0.f;
#pragma unroll 8
    for (int z2 = 0; z2 < 8; ++z2) s += qpart[(b * 8 + z2) * D + tid];
    qs[tid] = s + bq[tid];
    __syncthreads();
    const float4* q4 = (const float4*)qs;
    for (int r = 0; r < 8; ++r) {
        int d = z * 64 + wave * 8 + r;
        const float4* w4 = (const float4*)(Wk + (size_t)d * D);
        float4 a = w4[lane], qa = q4[lane];
        float4 b4 = w4[lane + 64], qb = q4[lane + 64];
        float acc = a.x*qa.x + a.y*qa.y + a.z*qa.z + a.w*qa.w
                  + b4.x*qb.x + b4.y*qb.y + b4.z*qb.z + b4.w*qb.w;
        for (int off = 32; off; off >>= 1) acc += __shfl_down(acc, off);
        if (lane == 0) wvec[b * D + d] = acc * RSQRT_D;
    }
    if (z == 0 && wave == 0) {
        float a = 0.f;
        for (int k = lane; k < D; k += 64) a += bk[k] * qs[k];
        for (int off = 32; off; off >>= 1) a += __shfl_down(a, off);
        if (lane == 0) cvec[b] = a * RSQRT_D;
    }
}

// ---------------------------------------------------------------------------
// K3: sc[b,s] = h[b,s,:] . wvec[b] + cvec[b].  grid (B,128) x 256 thr.
__global__ __launch_bounds__(256) void k_scores(const float* __restrict__ h,
                                                const float* __restrict__ wvec,
                                                const float* __restrict__ cvec,
                                                float* __restrict__ sc) {
    int b = blockIdx.x, s0 = blockIdx.y * 32, tid = threadIdx.x;
    int lane = tid & 63, wave = tid >> 6;
    __shared__ float wsv[D];
    wsv[tid] = wvec[b * D + tid];
    wsv[tid + 256] = wvec[b * D + tid + 256];
    __syncthreads();
    const float4* w4 = (const float4*)wsv;
    float cv = cvec[b];
    for (int r = 0; r < 8; ++r) {
        int s = s0 + wave * 8 + r;
        const float4* h4 = (const float4*)(h + ((size_t)b * T + s) * D);
        float4 a = h4[lane], wa = w4[lane];
        float4 b4 = h4[lane + 64], wb = w4[lane + 64];
        float acc = a.x*wa.x + a.y*wa.y + a.z*wa.z + a.w*wa.w
                  + b4.x*wb.x + b4.y*wb.y + b4.z*wb.z + b4.w*wb.w;
        for (int off = 32; off; off >>= 1) acc += __shfl_down(acc, off);
        if (lane == 0) sc[b * T + s] = acc + cv;
    }
}

// ---------------------------------------------------------------------------
// K4: per batch — exact top-1024 radix select; write normalized (idx, weight).
__global__ __launch_bounds__(1024) void k_select(const float* __restrict__ sc,
                                                 unsigned* __restrict__ selI,
                                                 float* __restrict__ selW) {
    int b = blockIdx.x, tid = threadIdx.x;
    int lane = tid & 63, wave = tid >> 6;
    __shared__ unsigned ordk[T];      // 16KB
    __shared__ unsigned tieI[T];      // 16KB
    __shared__ unsigned sI[KKEEP];    // 4KB
    __shared__ float sW[KKEEP];       // 4KB
    __shared__ int hist[256];
    __shared__ float red[16];
    __shared__ unsigned sh_pv;
    __shared__ int sh_r, sh_cnt, sh_tiecnt;
    __shared__ float sh_max, sh_inv;

    float sv[4];
    float lmax = -INFINITY;
#pragma unroll
    for (int k = 0; k < 4; ++k) {
        int i = tid + k * 1024;
        float v = sc[b * T + i];
        sv[k] = v;
        ordk[i] = f2ord(v);
        lmax = fmaxf(lmax, v);
    }
    for (int off = 32; off; off >>= 1) lmax = fmaxf(lmax, __shfl_down(lmax, off));
    if (lane == 0) red[wave] = lmax;
    __syncthreads();
    if (tid == 0) {
        float m = red[0];
        for (int w = 1; w < 16; ++w) m = fmaxf(m, red[w]);
        sh_max = m; sh_pv = 0; sh_r = KKEEP; sh_cnt = 0; sh_tiecnt = 0;
    }
    __syncthreads();

    for (int p = 24; p >= 0; p -= 8) {
        if (tid < 256) hist[tid] = 0;
        __syncthreads();
        unsigned pv = sh_pv;
#pragma unroll
        for (int k = 0; k < 4; ++k) {
            unsigned key = ordk[tid + k * 1024];
            bool act = (p == 24) || ((key >> (p + 8)) == pv);
            if (act) atomicAdd(&hist[(key >> p) & 255], 1);
        }
        __syncthreads();
        if (tid < 64) {  // wave 0: suffix-scan 256 bins, locate rank r
            int r = sh_r;
            int c0 = hist[tid*4], c1 = hist[tid*4+1], c2 = hist[tid*4+2], c3 = hist[tid*4+3];
            int ssum = c0 + c1 + c2 + c3;
            int cum = ssum;
            for (int off = 1; off < 64; off <<= 1) {
                int v = __shfl_down(cum, off);
                if (tid + off < 64) cum += v;
            }
            int base = cum - ssum;
            if (base < r && r <= cum) {  // exactly one lane
                int d, sg;
                if (r <= base + c3)                { d = 3; sg = base; }
                else if (r <= base + c3 + c2)      { d = 2; sg = base + c3; }
                else if (r <= base + c3 + c2 + c1) { d = 1; sg = base + c3 + c2; }
                else                               { d = 0; sg = base + c3 + c2 + c1; }
                sh_pv = (pv << 8) | (unsigned)(tid * 4 + d);
                sh_r = r - sg;
            }
        }
        __syncthreads();
    }

    unsigned vstar = sh_pv;
    int rtie = sh_r;
    float gmax = sh_max;

#pragma unroll
    for (int k = 0; k < 4; ++k) {
        int i = tid + k * 1024;
        unsigned key = ordk[i];
        if (key > vstar) {
            int pos = atomicAdd(&sh_cnt, 1);
            sI[pos] = (unsigned)i;
            sW[pos] = __expf(sv[k] - gmax);
        } else if (key == vstar) {
            int pos = atomicAdd(&sh_tiecnt, 1);
            tieI[pos] = (unsigned)i;
        }
    }
    __syncthreads();

    int tcnt = sh_tiecnt;
    float tw = __expf(ord2f(vstar) - gmax);
    for (int t = tid; t < tcnt; t += 1024) {
        unsigned my = tieI[t];
        int rank = 0;
        for (int o = 0; o < tcnt; ++o) rank += (tieI[o] < my);
        if (rank < rtie) {  // rtie smallest-index ties included
            int pos = atomicAdd(&sh_cnt, 1);
            sI[pos] = my;
            sW[pos] = tw;
        }
    }
    __syncthreads();

    float lsum = sW[tid];
    for (int off = 32; off; off >>= 1) lsum += __shfl_down(lsum, off);
    if (lane == 0) red[wave] = lsum;
    __syncthreads();
    if (tid == 0) {
        float ssum = 0.f;
        for (int w = 0; w < 16; ++w) ssum += red[w];
        sh_inv = 1.0f / ssum;
    }
    __syncthreads();
    selI[b * KKEEP + tid] = sI[tid];
    selW[b * KKEEP + tid] = sW[tid] * sh_inv;
}

// ---------------------------------------------------------------------------
// K5: part[b][y][:] = sum over 32 selected rows of w * h[b,idx,:]
// grid (B,32) x 512 thr = 4 groups x 128 lanes; no atomics.
__global__ __launch_bounds__(512) void k_wsum(const float* __restrict__ h,
                                              const unsigned* __restrict__ selI,
                                              const float* __restrict__ selW,
                                              float* __restrict__ part) {
    int b = blockIdx.x, y = blockIdx.y, tid = threadIdx.x;
    int g = tid >> 7, l = tid & 127;
    int e0 = y * 32;
    __shared__ float4 red4[512];
    float4 acc = make_float4(0.f, 0.f, 0.f, 0.f);
    for (int e = g; e < 32; e += 4) {
        unsigned s = selI[b * KKEEP + e0 + e];
        float w = selW[b * KKEEP + e0 + e];
        float4 v = ((const float4*)(h + ((size_t)b * T + s) * D))[l];
        acc.x += w * v.x; acc.y += w * v.y; acc.z += w * v.z; acc.w += w * v.w;
    }
    red4[tid] = acc;
    __syncthreads();
    if (tid < 128) {
        float4 a = red4[tid], b4 = red4[tid + 128], c = red4[tid + 256], d4 = red4[tid + 384];
        float4 r = make_float4(a.x + b4.x + c.x + d4.x, a.y + b4.y + c.y + d4.y,
                               a.z + b4.z + c.z + d4.z, a.w + b4.w + c.w + d4.w);
        ((float4*)part)[(b * 32 + y) * 128 + tid] = r;
    }
}

// ---------------------------------------------------------------------------
// K6: out[b, j0:j0+64] — reduce 32 gather-partials in LDS, then 8 d-group
// waves accumulate the Wv column-slice dot and LDS-reduce.
// grid (B,8) x 512 thr -> 32 blocks (round-9 fix: was 8 blocks, latency-bound).
__global__ __launch_bounds__(512) void k_out(const float* __restrict__ part,
                                             const float* __restrict__ Wv,
                                             const float* __restrict__ bv,
                                             float* __restrict__ out) {
    int b = blockIdx.x, j0 = blockIdx.y * 64, tid = threadIdx.x;
    int jl = tid & 63, dg = tid >> 6;  // 8 d-groups (one wave each)
    __shared__ float wsv[D];
    __shared__ float red[8][64];
    // Reduce the 32 gather partials -> wsv[0..511] (coalesced across tid).
    {
        float s = 0.f;
#pragma unroll 8
        for (int p = 0; p < 32; ++p) s += part[(size_t)(b * 32 + p) * D + tid];
        wsv[tid] = s;
    }
    __syncthreads();
    // Each wave dg handles d in [dg*64, dg*64+64), lanes = 64 consecutive j.
    float acc = 0.f;
    int d0 = dg * 64;
#pragma unroll 8
    for (int dd = 0; dd < 64; ++dd) {
        int d = d0 + dd;
        acc += wsv[d] * Wv[(size_t)d * D + j0 + jl];
    }
    red[dg][jl] = acc;
    __syncthreads();
    if (dg == 0) {
        float s = bv[j0 + jl];
#pragma unroll 8
        for (int g = 0; g < 8; ++g) s += red[g][jl];
        out[b * D + j0 + jl] = s;
    }
}

// ---------------------------------------------------------------------------
extern "C" void kernel_launch(void* const* d_in, const int* in_sizes, int n_in,
                              void* d_out, int out_size, void* d_ws, size_t ws_size,
                              hipStream_t stream) {
    const float* h  = (const float*)d_in[0];
    const float* Wq = (const float*)d_in[1];
    const float* bq = (const float*)d_in[2];
    const float* Wk = (const float*)d_in[3];
    const float* bk = (const float*)d_in[4];
    const float* Wv = (const float*)d_in[5];
    const float* bv = (const float*)d_in[6];
    float* out = (float*)d_out;

    float* ws = (float*)d_ws;
    float* qpart   = ws;                       // B*8*D = 16384
    float* wvec    = ws + 16384;               // B*D   = 2048
    float* cvec    = ws + 18432;               // B (pad 64)
    float* sc      = ws + 18496;               // B*T   = 16384
    unsigned* selI = (unsigned*)(ws + 34880);  // B*KKEEP = 4096
    float* selW    = ws + 38976;               // B*KKEEP = 4096
    float* part    = ws + 43072;               // B*32*D = 65536

    k_qpart<<<dim3(32), 512, 0, stream>>>(h, Wq, qpart);
    k_wk<<<dim3(32), 512, 0, stream>>>(Wk, bk, bq, qpart, wvec, cvec);
    k_scores<<<dim3(B, 128), 256, 0, stream>>>(h, wvec, cvec, sc);
    k_select<<<dim3(B), 1024, 0, stream>>>(sc, selI, selW);
    k_wsum<<<dim3(B, 32), 512, 0, stream>>>(h, selI, selW, part);
    k_out<<<dim3(B, 8), 512, 0, stream>>>(part, Wv, bv, out);
}